// Round 8
// baseline (329.874 us; speedup 1.0000x reference)
//
#include <hip/hip_runtime.h>
#include <math.h>

#define B_  4
#define T_  1024
#define C_  512
#define H_  8
#define D_  64
#define N3_ 1536
#define BT_ 4096

constexpr float kEps = 1e-5f;
constexpr float kNeg = -3.4028234663852886e38f;  // jnp.finfo(f32).min
constexpr float kMaskNeg = -1.4e38f;             // finite (log2e-domain mask)
constexpr float kLog2e = 1.44269504088896f;
constexpr float kShift2 = 17.312340490667562f;   // 12 * log2e

typedef __attribute__((ext_vector_type(8))) short bf16x8;
typedef __attribute__((ext_vector_type(4))) float f32x4;

__device__ __forceinline__ short f2bf(float f) {
  union { float f; unsigned u; } v; v.f = f;
  unsigned r = v.u + 0x7FFFu + ((v.u >> 16) & 1u);  // RNE
  return (short)(r >> 16);
}
__device__ __forceinline__ float bf2f(unsigned short b) {
  union { unsigned u; float f; } v;
  v.u = ((unsigned)b) << 16;
  return v.f;
}

// async global->LDS 16B/lane. LDS dest must be wave-uniform base; each lane
// lands at base + lane*16B (linear, no padding possible).
__device__ __forceinline__ void gld16(const void* g, void* l) {
  __builtin_amdgcn_global_load_lds(
      (const __attribute__((address_space(1))) unsigned int*)g,
      (__attribute__((address_space(3))) unsigned int*)l, 16, 0, 0);
}

// ------------------------------------------------ mask dtype canonicalize ---
// (fallback path only)
__global__ __launch_bounds__(64) void mask_detect_kernel(
    const unsigned int* __restrict__ m, int* __restrict__ flag) {
  int lane = threadIdx.x;
  int any_big = 0;
#pragma unroll
  for (int p = 0; p < 16; ++p) {
    unsigned int v = m[lane + p * 64];
    any_big |= (v > 1u);
  }
  unsigned long long b = __ballot(any_big);
  if (lane == 0) flag[0] = (b != 0ull) ? 1 : 0;  // 1 => byte-packed, 0 => int32
}

__global__ __launch_bounds__(256) void mask_convert_kernel(
    const void* __restrict__ mraw, const int* __restrict__ flag,
    uchar4* __restrict__ out) {
  int idx = blockIdx.x * 256 + threadIdx.x;
  uchar4 v;
  if (flag[0]) {
    v = ((const uchar4*)mraw)[idx];
    v.x = v.x ? 1 : 0; v.y = v.y ? 1 : 0; v.z = v.z ? 1 : 0; v.w = v.w ? 1 : 0;
  } else {
    int4 w = ((const int4*)mraw)[idx];
    v = make_uchar4(w.x != 0, w.y != 0, w.z != 0, w.w != 0);
  }
  out[idx] = v;
}

// --------------- pair [B,T,T,H] fp32 + mask -> biast [B,H,T,T] bf16 ---------
// Bias pre-scaled by log2e so attn softmax uses exp2 directly (validated r6/r7:
// identical absmax). The biast materialization converts attn's bias access
// from a latency-bound stride-32B gather (refuted r5: 139.7us attn) into
// coalesced 32B-contiguous bf16 loads.
__global__ __launch_bounds__(256) void pair_prep_kernel(
    const float* __restrict__ pair, const void* __restrict__ mraw,
    short* __restrict__ biast) {
  __shared__ short P[8][1024 + 8];
  unsigned wv = ((const unsigned*)mraw)[threadIdx.x];
  int is_u8 = __syncthreads_or(wv > 1u);
  int bi = blockIdx.x;  // b*1024 + i
  int b = bi >> 10, i = bi & 1023;
  int tid = threadIdx.x;
  const float* src = pair + (size_t)bi * (T_ * H_);
#pragma unroll
  for (int p = 0; p < 8; ++p) {
    int c = tid + p * 256;
    int j = c >> 1, hh = (c & 1) * 4;
    float4 v = *(const float4*)&src[c * 4];
    P[hh + 0][j] = f2bf(v.x * kLog2e);
    P[hh + 1][j] = f2bf(v.y * kLog2e);
    P[hh + 2][j] = f2bf(v.z * kLog2e);
    P[hh + 3][j] = f2bf(v.w * kLog2e);
  }
  bool mk[4];
  if (is_u8) {
    uchar4 mv = ((const uchar4*)mraw)[bi * 256 + tid];
    mk[0] = mv.x; mk[1] = mv.y; mk[2] = mv.z; mk[3] = mv.w;
  } else {
    int4 mv = ((const int4*)mraw)[bi * 256 + tid];
    mk[0] = mv.x != 0; mk[1] = mv.y != 0; mk[2] = mv.z != 0; mk[3] = mv.w != 0;
  }
  __syncthreads();
  const short negb = f2bf(kMaskNeg);
  int j = tid * 4;
#pragma unroll
  for (int h = 0; h < 8; ++h) {
    short4 o;
    o.x = mk[0] ? P[h][j + 0] : negb;
    o.y = mk[1] ? P[h][j + 1] : negb;
    o.z = mk[2] ? P[h][j + 2] : negb;
    o.w = mk[3] ? P[h][j + 3] : negb;
    *(short4*)&biast[((size_t)(b * 8 + h) * T_ + i) * T_ + j] = o;
  }
}

// ---------------------------------------- f32 -> bf16 cast, two buffers -----
// (fallback path only; main path uses prep_fused_kernel)
__global__ __launch_bounds__(256) void wcvt2_kernel(
    const float* __restrict__ a, short* __restrict__ oa,
    const float* __restrict__ b, short* __restrict__ ob, int nblk_a) {
  int bid = blockIdx.x;
  const float* src; short* dst; int idx;
  if (bid < nblk_a) { src = a; dst = oa; idx = bid * 256 + threadIdx.x; }
  else             { src = b; dst = ob; idx = (bid - nblk_a) * 256 + threadIdx.x; }
  int i = idx * 4;
  float4 v = *(const float4*)&src[i];
  short4 o;
  o.x = f2bf(v.x); o.y = f2bf(v.y); o.z = f2bf(v.z); o.w = f2bf(v.w);
  *(short4*)&dst[i] = o;
}

// --------------------------------------------------- LN(x) -> bf16 xn -------
// (fallback path only; main path uses prep_fused_kernel)
__global__ __launch_bounds__(128) void ln_x_kernel(
    const float* __restrict__ x, const float* __restrict__ w,
    const float* __restrict__ b, short* __restrict__ xn) {
  int row = blockIdx.x;
  int tid = threadIdx.x;
  const float* xr = x + (size_t)row * C_;
  float4 v = *(const float4*)&xr[tid * 4];
  float s  = v.x + v.y + v.z + v.w;
  float ss = v.x * v.x + v.y * v.y + v.z * v.z + v.w * v.w;
#pragma unroll
  for (int o = 32; o > 0; o >>= 1) {
    s  += __shfl_down(s, o);
    ss += __shfl_down(ss, o);
  }
  __shared__ float sh[4];
  int wid = tid >> 6, lane = tid & 63;
  if (lane == 0) { sh[wid] = s; sh[2 + wid] = ss; }
  __syncthreads();
  float m   = (sh[0] + sh[1]) * (1.0f / C_);
  float var = (sh[2] + sh[3]) * (1.0f / C_) - m * m;
  float inv = rsqrtf(var + kEps);
  float4 wv = *(const float4*)&w[tid * 4];
  float4 bv = *(const float4*)&b[tid * 4];
  short4 o4;
  o4.x = f2bf((v.x - m) * inv * wv.x + bv.x);
  o4.y = f2bf((v.y - m) * inv * wv.y + bv.y);
  o4.z = f2bf((v.z - m) * inv * wv.z + bv.z);
  o4.w = f2bf((v.w - m) * inv * wv.w + bv.w);
  *(short4*)&xn[(size_t)row * C_ + tid * 4] = o4;
}

// ----------- FUSED prep: LN(x) (blocks 0..4095) + weight casts --------------
// Block-uniform branch; saves one launch (~3us). Math identical to
// ln_x_kernel / wcvt2_kernel.
__global__ __launch_bounds__(128) void prep_fused_kernel(
    const float* __restrict__ x, const float* __restrict__ nw,
    const float* __restrict__ nb, short* __restrict__ xn,
    const float* __restrict__ qkv_w, short* __restrict__ wq,
    const float* __restrict__ proj_w, short* __restrict__ wp) {
  int bid = blockIdx.x;
  int tid = threadIdx.x;
  if (bid < BT_) {
    // ---- LN row ----
    const float* xr = x + (size_t)bid * C_;
    float4 v = *(const float4*)&xr[tid * 4];
    float s  = v.x + v.y + v.z + v.w;
    float ss = v.x * v.x + v.y * v.y + v.z * v.z + v.w * v.w;
#pragma unroll
    for (int o = 32; o > 0; o >>= 1) {
      s  += __shfl_down(s, o);
      ss += __shfl_down(ss, o);
    }
    __shared__ float sh[4];
    int wid = tid >> 6, lane = tid & 63;
    if (lane == 0) { sh[wid] = s; sh[2 + wid] = ss; }
    __syncthreads();
    float m   = (sh[0] + sh[1]) * (1.0f / C_);
    float var = (sh[2] + sh[3]) * (1.0f / C_) - m * m;
    float inv = rsqrtf(var + kEps);
    float4 wv = *(const float4*)&nw[tid * 4];
    float4 bv = *(const float4*)&nb[tid * 4];
    short4 o4;
    o4.x = f2bf((v.x - m) * inv * wv.x + bv.x);
    o4.y = f2bf((v.y - m) * inv * wv.y + bv.y);
    o4.z = f2bf((v.z - m) * inv * wv.z + bv.z);
    o4.w = f2bf((v.w - m) * inv * wv.w + bv.w);
    *(short4*)&xn[(size_t)bid * C_ + tid * 4] = o4;
  } else {
    // ---- weight bf16 cast: wq (1536 blocks) then wp (512 blocks) ----
    int idx = (bid - BT_) * 128 + tid;   // elems-of-4
    const float* src; short* dst;
    if (idx < (N3_ * C_) / 4) { src = qkv_w; dst = wq; }
    else { src = proj_w; dst = wp; idx -= (N3_ * C_) / 4; }
    int i = idx * 4;
    float4 v = *(const float4*)&src[i];
    short4 o;
    o.x = f2bf(v.x); o.y = f2bf(v.y); o.z = f2bf(v.z); o.w = f2bf(v.w);
    *(short4*)&dst[i] = o;
  }
}

// ------------------------- bf16 MFMA GEMM: 128x64 tile ----------------------
// (proven config: 768 blocks for gemm1 = 3/CU; global_load_lds 16B, linear LDS)
__global__ __launch_bounds__(256) void gemm_bf16_kernel(
    const short* __restrict__ A, const short* __restrict__ W,
    const float* __restrict__ bias, float* __restrict__ Cmat,
    int M, int N, int K) {
  __shared__ short As[128 * 64];
  __shared__ short Bs[64 * 64];
  int tid = threadIdx.x;
  int lane = tid & 63, wave = tid >> 6;
  int wm = wave >> 1, wn = wave & 1;
  int col = lane & 15, quad = lane >> 4;
  int m0 = blockIdx.y * 128, n0 = blockIdx.x * 64;
  int wbase = tid & ~63;  // wave-uniform

  f32x4 acc[4][2];
#pragma unroll
  for (int mi = 0; mi < 4; ++mi)
#pragma unroll
    for (int ni = 0; ni < 2; ++ni) acc[mi][ni] = {0.f, 0.f, 0.f, 0.f};

  for (int k0 = 0; k0 < K; k0 += 64) {
    __syncthreads();
#pragma unroll
    for (int p = 0; p < 4; ++p) {
      int c = tid + p * 256;
      int row = c >> 3, kc = (c & 7) * 8;
      gld16(&A[(size_t)(m0 + row) * K + k0 + kc], &As[(wbase + p * 256) * 8]);
    }
#pragma unroll
    for (int p = 0; p < 2; ++p) {
      int c = tid + p * 256;
      int row = c >> 3, kc = (c & 7) * 8;
      gld16(&W[(size_t)(n0 + row) * K + k0 + kc], &Bs[(wbase + p * 256) * 8]);
    }
    __syncthreads();
#pragma unroll
    for (int s = 0; s < 2; ++s) {
      bf16x8 af[4], bfv[2];
#pragma unroll
      for (int mi = 0; mi < 4; ++mi)
        af[mi] = *(const bf16x8*)&As[(64 * wm + 16 * mi + col) * 64 + s * 32 + quad * 8];
#pragma unroll
      for (int ni = 0; ni < 2; ++ni)
        bfv[ni] = *(const bf16x8*)&Bs[(32 * wn + 16 * ni + col) * 64 + s * 32 + quad * 8];
#pragma unroll
      for (int mi = 0; mi < 4; ++mi)
#pragma unroll
        for (int ni = 0; ni < 2; ++ni)
          acc[mi][ni] = __builtin_amdgcn_mfma_f32_16x16x32_bf16(
              af[mi], bfv[ni], acc[mi][ni], 0, 0, 0);
    }
  }
#pragma unroll
  for (int ni = 0; ni < 2; ++ni) {
    int n = n0 + 32 * wn + 16 * ni + col;
    float bv = bias[n];
#pragma unroll
    for (int mi = 0; mi < 4; ++mi) {
#pragma unroll
      for (int r = 0; r < 4; ++r) {
        int m = m0 + 64 * wm + 16 * mi + quad * 4 + r;
        Cmat[(size_t)m * N + n] = acc[mi][ni][r] + bv;
      }
    }
  }
}

// ------- gemm2 with FUSED merge: A = f2bf((O0+O1)/(l0+l1)), bit-identical ----
// For a k-block k0=kt*64, h=kt is constant, so A[m][k0:k0+64] maps to two
// CONTIGUOUS 64-float runs of Opart (+1 lpart pair) -> coalesced reg-staging
// with inline merge. Deletes the attn_merge launch and the ao round-trip.
// B stays gld16. Produces the exact same bf16 A bits as merge+gemm did.
__global__ __launch_bounds__(256) void gemm2_merge_kernel(
    const float* __restrict__ Opart, const float* __restrict__ lpart,
    const short* __restrict__ W, const float* __restrict__ bias,
    float* __restrict__ Cmat) {
  __shared__ short As[128 * 64];
  __shared__ short Bs[64 * 64];
  int tid = threadIdx.x;
  int lane = tid & 63, wave = tid >> 6;
  int wm = wave >> 1, wn = wave & 1;
  int col = lane & 15, quad = lane >> 4;
  int m0 = blockIdx.y * 128, n0 = blockIdx.x * 64;
  int wbase = tid & ~63;

  f32x4 acc[4][2];
#pragma unroll
  for (int mi = 0; mi < 4; ++mi)
#pragma unroll
    for (int ni = 0; ni < 2; ++ni) acc[mi][ni] = {0.f, 0.f, 0.f, 0.f};

  for (int kt = 0; kt < 8; ++kt) {   // k0 = kt*64, h = kt
    __syncthreads();
    // A-staging with inline merge: 4 chunks/thread, each 8 bf16.
#pragma unroll
    for (int p = 0; p < 4; ++p) {
      int c = tid + p * 256;            // [0,1024)
      int row = c >> 3, dc = (c & 7) * 8;
      int m = m0 + row;
      size_t orow = (size_t)((m >> 10) * 8 + kt) * 1024 + (m & 1023);
      const float* s0 = &Opart[orow * 64 + dc];
      const float* s1 = &Opart[((size_t)32768 + orow) * 64 + dc];
      float inv = 1.0f / (lpart[orow] + lpart[32768 + orow]);
      float4 a0 = *(const float4*)s0;
      float4 a1 = *(const float4*)(s0 + 4);
      float4 b0 = *(const float4*)s1;
      float4 b1 = *(const float4*)(s1 + 4);
      short o8[8];
      o8[0] = f2bf((a0.x + b0.x) * inv);
      o8[1] = f2bf((a0.y + b0.y) * inv);
      o8[2] = f2bf((a0.z + b0.z) * inv);
      o8[3] = f2bf((a0.w + b0.w) * inv);
      o8[4] = f2bf((a1.x + b1.x) * inv);
      o8[5] = f2bf((a1.y + b1.y) * inv);
      o8[6] = f2bf((a1.z + b1.z) * inv);
      o8[7] = f2bf((a1.w + b1.w) * inv);
      *(int4*)&As[row * 64 + dc] = *(const int4*)o8;
    }
    // B-staging via gld16 (unchanged)
#pragma unroll
    for (int p = 0; p < 2; ++p) {
      int c = tid + p * 256;
      int row = c >> 3, kc = (c & 7) * 8;
      gld16(&W[(size_t)(n0 + row) * C_ + kt * 64 + kc], &Bs[(wbase + p * 256) * 8]);
    }
    __syncthreads();
#pragma unroll
    for (int s = 0; s < 2; ++s) {
      bf16x8 af[4], bfv[2];
#pragma unroll
      for (int mi = 0; mi < 4; ++mi)
        af[mi] = *(const bf16x8*)&As[(64 * wm + 16 * mi + col) * 64 + s * 32 + quad * 8];
#pragma unroll
      for (int ni = 0; ni < 2; ++ni)
        bfv[ni] = *(const bf16x8*)&Bs[(32 * wn + 16 * ni + col) * 64 + s * 32 + quad * 8];
#pragma unroll
      for (int mi = 0; mi < 4; ++mi)
#pragma unroll
        for (int ni = 0; ni < 2; ++ni)
          acc[mi][ni] = __builtin_amdgcn_mfma_f32_16x16x32_bf16(
              af[mi], bfv[ni], acc[mi][ni], 0, 0, 0);
    }
  }
#pragma unroll
  for (int ni = 0; ni < 2; ++ni) {
    int n = n0 + 32 * wn + 16 * ni + col;
    float bv = bias[n];
#pragma unroll
    for (int mi = 0; mi < 4; ++mi) {
#pragma unroll
      for (int r = 0; r < 4; ++r) {
        int m = m0 + 64 * wm + 16 * mi + quad * 4 + r;
        Cmat[(size_t)m * C_ + n] = acc[mi][ni][r] + bv;
      }
    }
  }
}

// ------------- q/k LayerNorm + split into bf16 [B,H,T,D]; q pre-scaled ------
__global__ __launch_bounds__(128) void qkv_ln_split_kernel(
    const float* __restrict__ qkv,
    const float* __restrict__ qw, const float* __restrict__ qb,
    const float* __restrict__ kw, const float* __restrict__ kb,
    short* __restrict__ qh, short* __restrict__ kh, short* __restrict__ vh) {
  int row = blockIdx.x;
  int b = row >> 10, t = row & 1023;
  int tid = threadIdx.x;
  const float* base = qkv + (size_t)row * N3_;
  int c4 = tid * 4;
  float4 qv = *(const float4*)&base[c4];
  float4 kv = *(const float4*)&base[C_ + c4];
  float4 vv = *(const float4*)&base[2 * C_ + c4];
  float sq  = qv.x + qv.y + qv.z + qv.w;
  float sqq = qv.x * qv.x + qv.y * qv.y + qv.z * qv.z + qv.w * qv.w;
  float sk  = kv.x + kv.y + kv.z + kv.w;
  float skk = kv.x * kv.x + kv.y * kv.y + kv.z * kv.z + kv.w * kv.w;
#pragma unroll
  for (int o = 32; o > 0; o >>= 1) {
    sq  += __shfl_down(sq, o);
    sqq += __shfl_down(sqq, o);
    sk  += __shfl_down(sk, o);
    skk += __shfl_down(skk, o);
  }
  __shared__ float sh[8];
  int wid = tid >> 6, lane = tid & 63;
  if (lane == 0) { sh[wid] = sq; sh[2 + wid] = sqq; sh[4 + wid] = sk; sh[6 + wid] = skk; }
  __syncthreads();
  float qm   = (sh[0] + sh[1]) * (1.0f / C_);
  float qvar = (sh[2] + sh[3]) * (1.0f / C_) - qm * qm;
  float km   = (sh[4] + sh[5]) * (1.0f / C_);
  float kvar = (sh[6] + sh[7]) * (1.0f / C_) - km * km;
  float qi = rsqrtf(qvar + kEps);
  float ki = rsqrtf(kvar + kEps);
  float4 qwv = *(const float4*)&qw[c4];
  float4 qbv = *(const float4*)&qb[c4];
  float4 kwv = *(const float4*)&kw[c4];
  float4 kbv = *(const float4*)&kb[c4];
  int h = tid >> 4;
  int d = (tid & 15) * 4;
  size_t dst = ((size_t)(b * H_ + h) * T_ + t) * D_ + d;
  short4 qo, ko, vo;
  qo.x = f2bf(((qv.x - qm) * qi * qwv.x + qbv.x) * 0.125f);
  qo.y = f2bf(((qv.y - qm) * qi * qwv.y + qbv.y) * 0.125f);
  qo.z = f2bf(((qv.z - qm) * qi * qwv.z + qbv.z) * 0.125f);
  qo.w = f2bf(((qv.w - qm) * qi * qwv.w + qbv.w) * 0.125f);
  ko.x = f2bf((kv.x - km) * ki * kwv.x + kbv.x);
  ko.y = f2bf((kv.y - km) * ki * kwv.y + kbv.y);
  ko.z = f2bf((kv.z - km) * ki * kwv.z + kbv.z);
  ko.w = f2bf((kv.w - km) * ki * kwv.w + kbv.w);
  vo.x = f2bf(vv.x); vo.y = f2bf(vv.y); vo.z = f2bf(vv.z); vo.w = f2bf(vv.w);
  *(short4*)&qh[dst] = qo;
  *(short4*)&kh[dst] = ko;
  *(short4*)&vh[dst] = vo;
}

// --------- MFMA flash attention, fixed-shift softmax, 2-way j-split ---------
// grid (16, 32, 2): x=i-tile(64 rows), y=bh, z=j-half. 256 threads = 4 waves.
// (r6 lesson: at equal waves/CU, more/smaller blocks beat fewer/wider.)
// Bias loads issued AFTER the staging barrier, first use after the QK MFMAs.
// 2 barriers/tile: PV reads only its own wave's Ps rows (HW-validated r6/r7).
__global__ __launch_bounds__(256) void attn_split_kernel(
    const short* __restrict__ qh, const short* __restrict__ kh,
    const short* __restrict__ vh, const short* __restrict__ biast,
    float* __restrict__ Opart, float* __restrict__ lpart) {
  __shared__ short Ks[64 * 72];   // [j][d]
  __shared__ short Vt[64 * 72];   // [d][j]
  __shared__ short Ps[64 * 72];   // [i][j]
  int tid = threadIdx.x;
  int lane = tid & 63, w = tid >> 6;
  int col = lane & 15, quad = lane >> 4;
  int bh = blockIdx.y;
  int half = blockIdx.z;
  int i0 = blockIdx.x * 64;
  const short* Qg = qh + (size_t)bh * T_ * D_;
  const short* Kg = kh + (size_t)bh * T_ * D_;
  const short* Vg = vh + (size_t)bh * T_ * D_;
  const unsigned short* Bpu =
      (const unsigned short*)(biast + (size_t)bh * T_ * T_);

  bf16x8 qf[2];
#pragma unroll
  for (int s = 0; s < 2; ++s)
    qf[s] = *(const bf16x8*)&Qg[(size_t)(i0 + 16 * w + col) * D_ + s * 32 + quad * 8];

  float lsum[4];
  f32x4 oacc[4];
#pragma unroll
  for (int r = 0; r < 4; ++r) lsum[r] = 0.f;
#pragma unroll
  for (int dt = 0; dt < 4; ++dt) oacc[dt] = {0.f, 0.f, 0.f, 0.f};

  int jbase = half * (T_ / 2);
  for (int jj = 0; jj < T_ / 2; jj += 64) {
    int j0 = jbase + jj;
    __syncthreads();
    // stage K [j][d]
#pragma unroll
    for (int p = 0; p < 2; ++p) {
      int c = tid + p * 256;
      int row = c >> 3, dc = (c & 7) * 8;
      *(int4*)&Ks[row * 72 + dc] =
          *(const int4*)&Kg[(size_t)(j0 + row) * D_ + dc];
    }
    // stage V transposed -> Vt[d][j]
    {
      int j = tid & 63, d0 = (tid >> 6) * 16;
#pragma unroll
      for (int p = 0; p < 2; ++p) {
        short tmp[8];
        *(int4*)tmp = *(const int4*)&Vg[(size_t)(j0 + j) * D_ + d0 + p * 8];
#pragma unroll
        for (int q = 0; q < 8; ++q) Vt[(d0 + p * 8 + q) * 72 + j] = tmp[q];
      }
    }
    __syncthreads();

    // bias loads: after the barrier (not drained by it), coalesced from
    // biast; first use in softmax, after the QK MFMA cluster.
    unsigned short bsv[4][4];
#pragma unroll
    for (int r = 0; r < 4; ++r) {
      int gi = i0 + 16 * w + quad * 4 + r;
#pragma unroll
      for (int jt = 0; jt < 4; ++jt)
        bsv[r][jt] = Bpu[(size_t)gi * T_ + j0 + 16 * jt + col];
    }

    // S = Q·K^T
    f32x4 sacc[4];
#pragma unroll
    for (int jt = 0; jt < 4; ++jt) sacc[jt] = {0.f, 0.f, 0.f, 0.f};
#pragma unroll
    for (int s = 0; s < 2; ++s) {
#pragma unroll
      for (int jt = 0; jt < 4; ++jt) {
        bf16x8 kf = *(const bf16x8*)&Ks[(16 * jt + col) * 72 + s * 32 + quad * 8];
        sacc[jt] = __builtin_amdgcn_mfma_f32_16x16x32_bf16(qf[s], kf, sacc[jt], 0, 0, 0);
      }
    }

    // fixed-shift softmax numerator in exp2 domain; defer l reduction
#pragma unroll
    for (int r = 0; r < 4; ++r) {
      int li = 16 * w + quad * 4 + r;  // local i-row
#pragma unroll
      for (int jt = 0; jt < 4; ++jt) {
        float sv = fmaf(sacc[jt][r], kLog2e, bf2f(bsv[r][jt]));
        float p = exp2f(fminf(sv - kShift2, 86.5f));
        lsum[r] += p;
        Ps[li * 72 + 16 * jt + col] = f2bf(p);
      }
    }
    // no barrier: PV reads only this wave's own Ps rows (16w..16w+15);
    // wave-local LDS RAW is ordered by lgkmcnt (HW-validated r6/r7).

    // O += P·V
#pragma unroll
    for (int s = 0; s < 2; ++s) {
      bf16x8 pf = *(const bf16x8*)&Ps[(16 * w + col) * 72 + s * 32 + quad * 8];
#pragma unroll
      for (int dt = 0; dt < 4; ++dt) {
        bf16x8 vf = *(const bf16x8*)&Vt[(16 * dt + col) * 72 + s * 32 + quad * 8];
        oacc[dt] = __builtin_amdgcn_mfma_f32_16x16x32_bf16(pf, vf, oacc[dt], 0, 0, 0);
      }
    }
  }

  // epilogue: reduce l across the 16 lanes of each row, store partials
#pragma unroll
  for (int r = 0; r < 4; ++r) {
    float l = lsum[r];
#pragma unroll
    for (int o = 1; o < 16; o <<= 1) l += __shfl_xor(l, o);
    int gi = i0 + 16 * w + quad * 4 + r;
    size_t orow = (size_t)half * 32768 + (size_t)bh * T_ + gi;
    if (col == 0) lpart[orow] = l;
#pragma unroll
    for (int dt = 0; dt < 4; ++dt)
      Opart[orow * 64 + 16 * dt + col] = oacc[dt][r];
  }
}

// ------------- fallback attn (round-3 path, pair fp32 + uint8 mask) ---------
__global__ __launch_bounds__(256) void attn_kernel(
    const short* __restrict__ qh, const short* __restrict__ kh,
    const short* __restrict__ vh, const float* __restrict__ pair,
    const unsigned char* __restrict__ mask, short* __restrict__ ao) {
  __shared__ short Ks[64 * 72];
  __shared__ short Vt[64 * 72];
  __shared__ short Ps[64 * 72];
  int tid = threadIdx.x;
  int lane = tid & 63, w = tid >> 6;
  int col = lane & 15, quad = lane >> 4;
  int bh = blockIdx.y;
  int b = bh >> 3, h = bh & 7;
  int i0 = blockIdx.x * 64;
  const short* Qg = qh + (size_t)bh * T_ * D_;
  const short* Kg = kh + (size_t)bh * T_ * D_;
  const short* Vg = vh + (size_t)bh * T_ * D_;

  bf16x8 qf[2];
#pragma unroll
  for (int s = 0; s < 2; ++s)
    qf[s] = *(const bf16x8*)&Qg[(size_t)(i0 + 16 * w + col) * D_ + s * 32 + quad * 8];

  float mrun[4], lrun[4];
  f32x4 oacc[4];
#pragma unroll
  for (int r = 0; r < 4; ++r) { mrun[r] = -INFINITY; lrun[r] = 0.f; }
#pragma unroll
  for (int dt = 0; dt < 4; ++dt) oacc[dt] = {0.f, 0.f, 0.f, 0.f};

  for (int j0 = 0; j0 < T_; j0 += 64) {
    __syncthreads();
#pragma unroll
    for (int p = 0; p < 2; ++p) {
      int c = tid + p * 256;
      int row = c >> 3, dc = (c & 7) * 8;
      *(int4*)&Ks[row * 72 + dc] =
          *(const int4*)&Kg[(size_t)(j0 + row) * D_ + dc];
    }
    {
      int j = tid & 63, d0 = (tid >> 6) * 16;
#pragma unroll
      for (int p = 0; p < 2; ++p) {
        short tmp[8];
        *(int4*)tmp = *(const int4*)&Vg[(size_t)(j0 + j) * D_ + d0 + p * 8];
#pragma unroll
        for (int q = 0; q < 8; ++q) Vt[(d0 + p * 8 + q) * 72 + j] = tmp[q];
      }
    }
    __syncthreads();

    f32x4 sacc[4];
#pragma unroll
    for (int jt = 0; jt < 4; ++jt) sacc[jt] = {0.f, 0.f, 0.f, 0.f};
#pragma unroll
    for (int s = 0; s < 2; ++s) {
#pragma unroll
      for (int jt = 0; jt < 4; ++jt) {
        bf16x8 kf = *(const bf16x8*)&Ks[(16 * jt + col) * 72 + s * 32 + quad * 8];
        sacc[jt] = __builtin_amdgcn_mfma_f32_16x16x32_bf16(qf[s], kf, sacc[jt], 0, 0, 0);
      }
    }

#pragma unroll
    for (int r = 0; r < 4; ++r) {
      int gi = i0 + 16 * w + quad * 4 + r;
      const float* prow = pair + (size_t)(b * T_ + gi) * (T_ * H_) + h;
      const unsigned char* mrow = mask + (size_t)(b * T_ + gi) * T_;
      float sv[4];
      float rm = -INFINITY;
#pragma unroll
      for (int jt = 0; jt < 4; ++jt) {
        int j = j0 + 16 * jt + col;
        float s = sacc[jt][r] + prow[(size_t)j * H_];
        if (!mrow[j]) s += kNeg;
        sv[jt] = s;
        rm = fmaxf(rm, s);
      }
#pragma unroll
      for (int o = 8; o > 0; o >>= 1) rm = fmaxf(rm, __shfl_xor(rm, o));
      float mnew  = fmaxf(mrun[r], rm);
      float alpha = __expf(mrun[r] - mnew);
      float psum = 0.f;
#pragma unroll
      for (int jt = 0; jt < 4; ++jt) {
        float p = __expf(sv[jt] - mnew);
        psum += p;
        Ps[(16 * w + quad * 4 + r) * 72 + 16 * jt + col] = f2bf(p);
      }
#pragma unroll
      for (int o = 8; o > 0; o >>= 1) psum += __shfl_xor(psum, o);
      lrun[r] = lrun[r] * alpha + psum;
      mrun[r] = mnew;
#pragma unroll
      for (int dt = 0; dt < 4; ++dt) oacc[dt][r] *= alpha;
    }
    __syncthreads();

#pragma unroll
    for (int s = 0; s < 2; ++s) {
      bf16x8 pf = *(const bf16x8*)&Ps[(16 * w + col) * 72 + s * 32 + quad * 8];
#pragma unroll
      for (int dt = 0; dt < 4; ++dt) {
        bf16x8 vf = *(const bf16x8*)&Vt[(16 * dt + col) * 72 + s * 32 + quad * 8];
        oacc[dt] = __builtin_amdgcn_mfma_f32_16x16x32_bf16(pf, vf, oacc[dt], 0, 0, 0);
      }
    }
  }

#pragma unroll
  for (int r = 0; r < 4; ++r) {
    int gi = i0 + 16 * w + quad * 4 + r;
    float inv = 1.0f / lrun[r];
    size_t base = (size_t)(b * T_ + gi) * C_ + h * D_;
#pragma unroll
    for (int dt = 0; dt < 4; ++dt)
      ao[base + 16 * dt + col] = f2bf(oacc[dt][r] * inv);
  }
}

// ---------------------------------------------------------------------------
extern "C" void kernel_launch(void* const* d_in, const int* in_sizes, int n_in,
                              void* d_out, int out_size, void* d_ws, size_t ws_size,
                              hipStream_t stream) {
  const float* x      = (const float*)d_in[0];
  const float* pair   = (const float*)d_in[1];
  const void*  maskraw = d_in[2];
  const float* norm_w = (const float*)d_in[3];
  const float* norm_b = (const float*)d_in[4];
  const float* qkv_w  = (const float*)d_in[5];
  const float* qkv_b  = (const float*)d_in[6];
  const float* qln_w  = (const float*)d_in[7];
  const float* qln_b  = (const float*)d_in[8];
  const float* kln_w  = (const float*)d_in[9];
  const float* kln_b  = (const float*)d_in[10];
  const float* proj_w = (const float*)d_in[11];
  const float* proj_b = (const float*)d_in[12];
  float* out = (float*)d_out;

  // d_out doubles as scratch: [0,4MB) xn bf16, [4,8MB) qh bf16.
  short* xn = (short*)d_out;
  short* qh = (short*)d_out + (size_t)BT_ * C_;

  const size_t MB = 1024 * 1024;

  if (ws_size >= 96 * MB) {
    // ws layout (r1-proven):
    //   [0,64MB)    biast bf16 [B,H,T,T] (written by prep AFTER split)
    //   [0,24MB)    qkv fp32 (live gemm->split only; overlaid by biast)
    //   [64,80MB)   Opart fp32 [2][32][1024][64]
    //   [80,80.25)  lpart fp32 [2][32][1024]
    //   [85,89MB)   kh bf16    [89,93MB) vh bf16
    //   [93,94.5MB) wq bf16    [94.5,95MB) wp bf16
    char* base = (char*)d_ws;
    short* biast = (short*)base;
    float* qkv   = (float*)base;
    float* Opart = (float*)(base + 64 * MB);
    float* lpart = (float*)(base + 80 * MB);
    short* kh    = (short*)(base + 85 * MB);
    short* vh    = (short*)(base + 89 * MB);
    short* wq    = (short*)(base + 93 * MB);
    short* wp    = (short*)(base + 94 * MB + 512 * 1024);

    prep_fused_kernel<<<BT_ + (N3_ * C_ + C_ * C_) / 512, 128, 0, stream>>>(
        x, norm_w, norm_b, xn, qkv_w, wq, proj_w, wp);
    gemm_bf16_kernel<<<dim3(N3_ / 64, BT_ / 128), 256, 0, stream>>>(
        xn, wq, qkv_b, qkv, BT_, N3_, C_);
    qkv_ln_split_kernel<<<BT_, 128, 0, stream>>>(
        qkv, qln_w, qln_b, kln_w, kln_b, qh, kh, vh);
    pair_prep_kernel<<<B_ * T_, 256, 0, stream>>>(pair, maskraw, biast);
    attn_split_kernel<<<dim3(T_ / 64, B_ * H_, 2), 256, 0, stream>>>(
        qh, kh, vh, biast, Opart, lpart);
    gemm2_merge_kernel<<<dim3(C_ / 64, BT_ / 128), 256, 0, stream>>>(
        Opart, lpart, wp, proj_b, out);
  } else {
    // Fallback: round-3 layout (38 MB + 4B).
    float* qkv = (float*)d_ws;
    short* ao  = (short*)d_ws;
    short* sw  = (short*)d_ws;
    short* wq  = sw + (size_t)12 * 1024 * 1024;
    short* wp  = wq + (size_t)N3_ * C_;
    short* kh  = sw + (size_t)13 * 1024 * 1024;
    short* vh  = sw + (size_t)15 * 1024 * 1024;
    unsigned char* maskc = (unsigned char*)d_ws + (size_t)34 * MB;
    int* flag = (int*)((unsigned char*)d_ws + (size_t)38 * MB);

    mask_detect_kernel<<<1, 64, 0, stream>>>((const unsigned int*)maskraw, flag);
    mask_convert_kernel<<<(B_ * T_ * T_) / 1024, 256, 0, stream>>>(
        maskraw, flag, (uchar4*)maskc);
    wcvt2_kernel<<<(N3_ * C_ + C_ * C_) / 1024, 256, 0, stream>>>(
        qkv_w, wq, proj_w, wp, (N3_ * C_) / 1024);
    ln_x_kernel<<<BT_, 128, 0, stream>>>(x, norm_w, norm_b, xn);
    gemm_bf16_kernel<<<dim3(N3_ / 64, BT_ / 128), 256, 0, stream>>>(
        xn, wq, qkv_b, qkv, BT_, N3_, C_);
    qkv_ln_split_kernel<<<BT_, 128, 0, stream>>>(
        qkv, qln_w, qln_b, kln_w, kln_b, qh, kh, vh);
    attn_kernel<<<dim3(T_ / 64, B_ * H_), 256, 0, stream>>>(
        qh, kh, vh, pair, maskc, ao);
    gemm_bf16_kernel<<<dim3(C_ / 64, BT_ / 128), 256, 0, stream>>>(
        ao, wp, proj_b, out, BT_, C_, C_);
  }
}

// Round 9
// 305.928 us; speedup vs baseline: 1.0783x; 1.0783x over previous
//
#include <hip/hip_runtime.h>
#include <math.h>

#define B_  4
#define T_  1024
#define C_  512
#define H_  8
#define D_  64
#define N3_ 1536
#define BT_ 4096

constexpr float kEps = 1e-5f;
constexpr float kNeg = -3.4028234663852886e38f;  // jnp.finfo(f32).min
constexpr float kMaskNeg = -1e38f;               // finite, bf16-representable
constexpr float kShift = 12.0f;                  // fixed softmax shift

typedef __attribute__((ext_vector_type(8))) short bf16x8;
typedef __attribute__((ext_vector_type(4))) float f32x4;

__device__ __forceinline__ short f2bf(float f) {
  union { float f; unsigned u; } v; v.f = f;
  unsigned r = v.u + 0x7FFFu + ((v.u >> 16) & 1u);  // RNE
  return (short)(r >> 16);
}
__device__ __forceinline__ float bf2f(unsigned short b) {
  union { unsigned u; float f; } v;
  v.u = ((unsigned)b) << 16;
  return v.f;
}

// async global->LDS 16B/lane. LDS dest must be wave-uniform base; each lane
// lands at base + lane*16B (linear, no padding possible).
__device__ __forceinline__ void gld16(const void* g, void* l) {
  __builtin_amdgcn_global_load_lds(
      (const __attribute__((address_space(1))) unsigned int*)g,
      (__attribute__((address_space(3))) unsigned int*)l, 16, 0, 0);
}

// ------------------------------------------------ mask dtype canonicalize ---
// (fallback path only)
__global__ __launch_bounds__(64) void mask_detect_kernel(
    const unsigned int* __restrict__ m, int* __restrict__ flag) {
  int lane = threadIdx.x;
  int any_big = 0;
#pragma unroll
  for (int p = 0; p < 16; ++p) {
    unsigned int v = m[lane + p * 64];
    any_big |= (v > 1u);
  }
  unsigned long long b = __ballot(any_big);
  if (lane == 0) flag[0] = (b != 0ull) ? 1 : 0;  // 1 => byte-packed, 0 => int32
}

__global__ __launch_bounds__(256) void mask_convert_kernel(
    const void* __restrict__ mraw, const int* __restrict__ flag,
    uchar4* __restrict__ out) {
  int idx = blockIdx.x * 256 + threadIdx.x;
  uchar4 v;
  if (flag[0]) {
    v = ((const uchar4*)mraw)[idx];
    v.x = v.x ? 1 : 0; v.y = v.y ? 1 : 0; v.z = v.z ? 1 : 0; v.w = v.w ? 1 : 0;
  } else {
    int4 w = ((const int4*)mraw)[idx];
    v = make_uchar4(w.x != 0, w.y != 0, w.z != 0, w.w != 0);
  }
  out[idx] = v;
}

// --------------- pair [B,T,T,H] fp32 + mask -> biast [B,H,T,T] bf16 ---------
// (r1-exact: plain domain, no log2e.) The biast materialization converts
// attn's bias access from a latency-bound stride-32B gather (refuted r5:
// 139.7us attn) into coalesced 32B-contiguous bf16 loads.
__global__ __launch_bounds__(256) void pair_prep_kernel(
    const float* __restrict__ pair, const void* __restrict__ mraw,
    short* __restrict__ biast) {
  __shared__ short P[8][1024 + 8];
  unsigned wv = ((const unsigned*)mraw)[threadIdx.x];
  int is_u8 = __syncthreads_or(wv > 1u);
  int bi = blockIdx.x;  // b*1024 + i
  int b = bi >> 10, i = bi & 1023;
  int tid = threadIdx.x;
  const float* src = pair + (size_t)bi * (T_ * H_);
#pragma unroll
  for (int p = 0; p < 8; ++p) {
    int c = tid + p * 256;
    int j = c >> 1, hh = (c & 1) * 4;
    float4 v = *(const float4*)&src[c * 4];
    P[hh + 0][j] = f2bf(v.x);
    P[hh + 1][j] = f2bf(v.y);
    P[hh + 2][j] = f2bf(v.z);
    P[hh + 3][j] = f2bf(v.w);
  }
  bool mk[4];
  if (is_u8) {
    uchar4 mv = ((const uchar4*)mraw)[bi * 256 + tid];
    mk[0] = mv.x; mk[1] = mv.y; mk[2] = mv.z; mk[3] = mv.w;
  } else {
    int4 mv = ((const int4*)mraw)[bi * 256 + tid];
    mk[0] = mv.x != 0; mk[1] = mv.y != 0; mk[2] = mv.z != 0; mk[3] = mv.w != 0;
  }
  __syncthreads();
  const short negb = f2bf(kMaskNeg);
  int j = tid * 4;
#pragma unroll
  for (int h = 0; h < 8; ++h) {
    short4 o;
    o.x = mk[0] ? P[h][j + 0] : negb;
    o.y = mk[1] ? P[h][j + 1] : negb;
    o.z = mk[2] ? P[h][j + 2] : negb;
    o.w = mk[3] ? P[h][j + 3] : negb;
    *(short4*)&biast[((size_t)(b * 8 + h) * T_ + i) * T_ + j] = o;
  }
}

// ---------------------------------------- f32 -> bf16 cast, two buffers -----
// (fallback path only; main path uses prep_fused_kernel)
__global__ __launch_bounds__(256) void wcvt2_kernel(
    const float* __restrict__ a, short* __restrict__ oa,
    const float* __restrict__ b, short* __restrict__ ob, int nblk_a) {
  int bid = blockIdx.x;
  const float* src; short* dst; int idx;
  if (bid < nblk_a) { src = a; dst = oa; idx = bid * 256 + threadIdx.x; }
  else             { src = b; dst = ob; idx = (bid - nblk_a) * 256 + threadIdx.x; }
  int i = idx * 4;
  float4 v = *(const float4*)&src[i];
  short4 o;
  o.x = f2bf(v.x); o.y = f2bf(v.y); o.z = f2bf(v.z); o.w = f2bf(v.w);
  *(short4*)&dst[i] = o;
}

// --------------------------------------------------- LN(x) -> bf16 xn -------
// (fallback path only; main path uses prep_fused_kernel)
__global__ __launch_bounds__(128) void ln_x_kernel(
    const float* __restrict__ x, const float* __restrict__ w,
    const float* __restrict__ b, short* __restrict__ xn) {
  int row = blockIdx.x;
  int tid = threadIdx.x;
  const float* xr = x + (size_t)row * C_;
  float4 v = *(const float4*)&xr[tid * 4];
  float s  = v.x + v.y + v.z + v.w;
  float ss = v.x * v.x + v.y * v.y + v.z * v.z + v.w * v.w;
#pragma unroll
  for (int o = 32; o > 0; o >>= 1) {
    s  += __shfl_down(s, o);
    ss += __shfl_down(ss, o);
  }
  __shared__ float sh[4];
  int wid = tid >> 6, lane = tid & 63;
  if (lane == 0) { sh[wid] = s; sh[2 + wid] = ss; }
  __syncthreads();
  float m   = (sh[0] + sh[1]) * (1.0f / C_);
  float var = (sh[2] + sh[3]) * (1.0f / C_) - m * m;
  float inv = rsqrtf(var + kEps);
  float4 wv = *(const float4*)&w[tid * 4];
  float4 bv = *(const float4*)&b[tid * 4];
  short4 o4;
  o4.x = f2bf((v.x - m) * inv * wv.x + bv.x);
  o4.y = f2bf((v.y - m) * inv * wv.y + bv.y);
  o4.z = f2bf((v.z - m) * inv * wv.z + bv.z);
  o4.w = f2bf((v.w - m) * inv * wv.w + bv.w);
  *(short4*)&xn[(size_t)row * C_ + tid * 4] = o4;
}

// ----------- FUSED prep: LN(x) (blocks 0..4095) + weight casts --------------
// Block-uniform branch; saves one launch. Math identical to
// ln_x_kernel / wcvt2_kernel (r8-validated correctness).
__global__ __launch_bounds__(128) void prep_fused_kernel(
    const float* __restrict__ x, const float* __restrict__ nw,
    const float* __restrict__ nb, short* __restrict__ xn,
    const float* __restrict__ qkv_w, short* __restrict__ wq,
    const float* __restrict__ proj_w, short* __restrict__ wp) {
  int bid = blockIdx.x;
  int tid = threadIdx.x;
  if (bid < BT_) {
    const float* xr = x + (size_t)bid * C_;
    float4 v = *(const float4*)&xr[tid * 4];
    float s  = v.x + v.y + v.z + v.w;
    float ss = v.x * v.x + v.y * v.y + v.z * v.z + v.w * v.w;
#pragma unroll
    for (int o = 32; o > 0; o >>= 1) {
      s  += __shfl_down(s, o);
      ss += __shfl_down(ss, o);
    }
    __shared__ float sh[4];
    int wid = tid >> 6, lane = tid & 63;
    if (lane == 0) { sh[wid] = s; sh[2 + wid] = ss; }
    __syncthreads();
    float m   = (sh[0] + sh[1]) * (1.0f / C_);
    float var = (sh[2] + sh[3]) * (1.0f / C_) - m * m;
    float inv = rsqrtf(var + kEps);
    float4 wv = *(const float4*)&nw[tid * 4];
    float4 bv = *(const float4*)&nb[tid * 4];
    short4 o4;
    o4.x = f2bf((v.x - m) * inv * wv.x + bv.x);
    o4.y = f2bf((v.y - m) * inv * wv.y + bv.y);
    o4.z = f2bf((v.z - m) * inv * wv.z + bv.z);
    o4.w = f2bf((v.w - m) * inv * wv.w + bv.w);
    *(short4*)&xn[(size_t)bid * C_ + tid * 4] = o4;
  } else {
    int idx = (bid - BT_) * 128 + tid;   // elems-of-4
    const float* src; short* dst;
    if (idx < (N3_ * C_) / 4) { src = qkv_w; dst = wq; }
    else { src = proj_w; dst = wp; idx -= (N3_ * C_) / 4; }
    int i = idx * 4;
    float4 v = *(const float4*)&src[i];
    short4 o;
    o.x = f2bf(v.x); o.y = f2bf(v.y); o.z = f2bf(v.z); o.w = f2bf(v.w);
    *(short4*)&dst[i] = o;
  }
}

// ------------------------- bf16 MFMA GEMM: 128x64 tile ----------------------
// (proven config for gemm1: 768 blocks = 3/CU; global_load_lds 16B, linear LDS)
__global__ __launch_bounds__(256) void gemm_bf16_kernel(
    const short* __restrict__ A, const short* __restrict__ W,
    const float* __restrict__ bias, float* __restrict__ Cmat,
    int M, int N, int K) {
  __shared__ short As[128 * 64];
  __shared__ short Bs[64 * 64];
  int tid = threadIdx.x;
  int lane = tid & 63, wave = tid >> 6;
  int wm = wave >> 1, wn = wave & 1;
  int col = lane & 15, quad = lane >> 4;
  int m0 = blockIdx.y * 128, n0 = blockIdx.x * 64;
  int wbase = tid & ~63;  // wave-uniform

  f32x4 acc[4][2];
#pragma unroll
  for (int mi = 0; mi < 4; ++mi)
#pragma unroll
    for (int ni = 0; ni < 2; ++ni) acc[mi][ni] = {0.f, 0.f, 0.f, 0.f};

  for (int k0 = 0; k0 < K; k0 += 64) {
    __syncthreads();
#pragma unroll
    for (int p = 0; p < 4; ++p) {
      int c = tid + p * 256;
      int row = c >> 3, kc = (c & 7) * 8;
      gld16(&A[(size_t)(m0 + row) * K + k0 + kc], &As[(wbase + p * 256) * 8]);
    }
#pragma unroll
    for (int p = 0; p < 2; ++p) {
      int c = tid + p * 256;
      int row = c >> 3, kc = (c & 7) * 8;
      gld16(&W[(size_t)(n0 + row) * K + k0 + kc], &Bs[(wbase + p * 256) * 8]);
    }
    __syncthreads();
#pragma unroll
    for (int s = 0; s < 2; ++s) {
      bf16x8 af[4], bfv[2];
#pragma unroll
      for (int mi = 0; mi < 4; ++mi)
        af[mi] = *(const bf16x8*)&As[(64 * wm + 16 * mi + col) * 64 + s * 32 + quad * 8];
#pragma unroll
      for (int ni = 0; ni < 2; ++ni)
        bfv[ni] = *(const bf16x8*)&Bs[(32 * wn + 16 * ni + col) * 64 + s * 32 + quad * 8];
#pragma unroll
      for (int mi = 0; mi < 4; ++mi)
#pragma unroll
        for (int ni = 0; ni < 2; ++ni)
          acc[mi][ni] = __builtin_amdgcn_mfma_f32_16x16x32_bf16(
              af[mi], bfv[ni], acc[mi][ni], 0, 0, 0);
    }
  }
#pragma unroll
  for (int ni = 0; ni < 2; ++ni) {
    int n = n0 + 32 * wn + 16 * ni + col;
    float bv = bias[n];
#pragma unroll
    for (int mi = 0; mi < 4; ++mi) {
#pragma unroll
      for (int r = 0; r < 4; ++r) {
        int m = m0 + 64 * wm + 16 * mi + quad * 4 + r;
        Cmat[(size_t)m * N + n] = acc[mi][ni][r] + bv;
      }
    }
  }
}

// ------------------- bf16 MFMA GEMM: 64x64 tile (for gemm2) -----------------
// gemm2 at 128x64 gives grid 256 = 1 block/CU: every K-step's vmcnt(0) drain
// is fully exposed. 64x64 doubles the grid to 512 = 2/CU so a partner block
// hides each drain. Same math/accumulation order per output element.
__global__ __launch_bounds__(256) void gemm_bf16_64_kernel(
    const short* __restrict__ A, const short* __restrict__ W,
    const float* __restrict__ bias, float* __restrict__ Cmat,
    int M, int N, int K) {
  __shared__ short As[64 * 64];
  __shared__ short Bs[64 * 64];
  int tid = threadIdx.x;
  int lane = tid & 63, wave = tid >> 6;
  int wm = wave >> 1, wn = wave & 1;
  int col = lane & 15, quad = lane >> 4;
  int m0 = blockIdx.y * 64, n0 = blockIdx.x * 64;
  int wbase = tid & ~63;  // wave-uniform

  f32x4 acc[2][2];
#pragma unroll
  for (int mi = 0; mi < 2; ++mi)
#pragma unroll
    for (int ni = 0; ni < 2; ++ni) acc[mi][ni] = {0.f, 0.f, 0.f, 0.f};

  for (int k0 = 0; k0 < K; k0 += 64) {
    __syncthreads();
#pragma unroll
    for (int p = 0; p < 2; ++p) {
      int c = tid + p * 256;
      int row = c >> 3, kc = (c & 7) * 8;
      gld16(&A[(size_t)(m0 + row) * K + k0 + kc], &As[(wbase + p * 256) * 8]);
    }
#pragma unroll
    for (int p = 0; p < 2; ++p) {
      int c = tid + p * 256;
      int row = c >> 3, kc = (c & 7) * 8;
      gld16(&W[(size_t)(n0 + row) * K + k0 + kc], &Bs[(wbase + p * 256) * 8]);
    }
    __syncthreads();
#pragma unroll
    for (int s = 0; s < 2; ++s) {
      bf16x8 af[2], bfv[2];
#pragma unroll
      for (int mi = 0; mi < 2; ++mi)
        af[mi] = *(const bf16x8*)&As[(32 * wm + 16 * mi + col) * 64 + s * 32 + quad * 8];
#pragma unroll
      for (int ni = 0; ni < 2; ++ni)
        bfv[ni] = *(const bf16x8*)&Bs[(32 * wn + 16 * ni + col) * 64 + s * 32 + quad * 8];
#pragma unroll
      for (int mi = 0; mi < 2; ++mi)
#pragma unroll
        for (int ni = 0; ni < 2; ++ni)
          acc[mi][ni] = __builtin_amdgcn_mfma_f32_16x16x32_bf16(
              af[mi], bfv[ni], acc[mi][ni], 0, 0, 0);
    }
  }
#pragma unroll
  for (int ni = 0; ni < 2; ++ni) {
    int n = n0 + 32 * wn + 16 * ni + col;
    float bv = bias[n];
#pragma unroll
    for (int mi = 0; mi < 2; ++mi) {
#pragma unroll
      for (int r = 0; r < 4; ++r) {
        int m = m0 + 32 * wm + 16 * mi + quad * 4 + r;
        Cmat[(size_t)m * N + n] = acc[mi][ni][r] + bv;
      }
    }
  }
}

// ------------- q/k LayerNorm + split into bf16 [B,H,T,D]; q pre-scaled ------
__global__ __launch_bounds__(128) void qkv_ln_split_kernel(
    const float* __restrict__ qkv,
    const float* __restrict__ qw, const float* __restrict__ qb,
    const float* __restrict__ kw, const float* __restrict__ kb,
    short* __restrict__ qh, short* __restrict__ kh, short* __restrict__ vh) {
  int row = blockIdx.x;
  int b = row >> 10, t = row & 1023;
  int tid = threadIdx.x;
  const float* base = qkv + (size_t)row * N3_;
  int c4 = tid * 4;
  float4 qv = *(const float4*)&base[c4];
  float4 kv = *(const float4*)&base[C_ + c4];
  float4 vv = *(const float4*)&base[2 * C_ + c4];
  float sq  = qv.x + qv.y + qv.z + qv.w;
  float sqq = qv.x * qv.x + qv.y * qv.y + qv.z * qv.z + qv.w * qv.w;
  float sk  = kv.x + kv.y + kv.z + kv.w;
  float skk = kv.x * kv.x + kv.y * kv.y + kv.z * kv.z + kv.w * kv.w;
#pragma unroll
  for (int o = 32; o > 0; o >>= 1) {
    sq  += __shfl_down(sq, o);
    sqq += __shfl_down(sqq, o);
    sk  += __shfl_down(sk, o);
    skk += __shfl_down(skk, o);
  }
  __shared__ float sh[8];
  int wid = tid >> 6, lane = tid & 63;
  if (lane == 0) { sh[wid] = sq; sh[2 + wid] = sqq; sh[4 + wid] = sk; sh[6 + wid] = skk; }
  __syncthreads();
  float qm   = (sh[0] + sh[1]) * (1.0f / C_);
  float qvar = (sh[2] + sh[3]) * (1.0f / C_) - qm * qm;
  float km   = (sh[4] + sh[5]) * (1.0f / C_);
  float kvar = (sh[6] + sh[7]) * (1.0f / C_) - km * km;
  float qi = rsqrtf(qvar + kEps);
  float ki = rsqrtf(kvar + kEps);
  float4 qwv = *(const float4*)&qw[c4];
  float4 qbv = *(const float4*)&qb[c4];
  float4 kwv = *(const float4*)&kw[c4];
  float4 kbv = *(const float4*)&kb[c4];
  int h = tid >> 4;
  int d = (tid & 15) * 4;
  size_t dst = ((size_t)(b * H_ + h) * T_ + t) * D_ + d;
  short4 qo, ko, vo;
  qo.x = f2bf(((qv.x - qm) * qi * qwv.x + qbv.x) * 0.125f);
  qo.y = f2bf(((qv.y - qm) * qi * qwv.y + qbv.y) * 0.125f);
  qo.z = f2bf(((qv.z - qm) * qi * qwv.z + qbv.z) * 0.125f);
  qo.w = f2bf(((qv.w - qm) * qi * qwv.w + qbv.w) * 0.125f);
  ko.x = f2bf((kv.x - km) * ki * kwv.x + kbv.x);
  ko.y = f2bf((kv.y - km) * ki * kwv.y + kbv.y);
  ko.z = f2bf((kv.z - km) * ki * kwv.z + kbv.z);
  ko.w = f2bf((kv.w - km) * ki * kwv.w + kbv.w);
  vo.x = f2bf(vv.x); vo.y = f2bf(vv.y); vo.z = f2bf(vv.z); vo.w = f2bf(vv.w);
  *(short4*)&qh[dst] = qo;
  *(short4*)&kh[dst] = ko;
  *(short4*)&vh[dst] = vo;
}

// --------- MFMA flash attention, fixed-shift softmax, 2-way j-split ---------
// r1-EXACT (measured best 308.1us): grid (16, 32, 2), 256 threads = 4 waves,
// 3 barriers/tile, expf, bias loaded after the staging barrier (coalesced from
// biast, first use after the QK MFMA cluster).
__global__ __launch_bounds__(256) void attn_split_kernel(
    const short* __restrict__ qh, const short* __restrict__ kh,
    const short* __restrict__ vh, const short* __restrict__ biast,
    float* __restrict__ Opart, float* __restrict__ lpart) {
  __shared__ short Ks[64 * 72];   // [j][d]
  __shared__ short Vt[64 * 72];   // [d][j]
  __shared__ short Ps[64 * 72];   // [i][j]
  int tid = threadIdx.x;
  int lane = tid & 63, w = tid >> 6;
  int col = lane & 15, quad = lane >> 4;
  int bh = blockIdx.y;
  int half = blockIdx.z;
  int i0 = blockIdx.x * 64;
  const short* Qg = qh + (size_t)bh * T_ * D_;
  const short* Kg = kh + (size_t)bh * T_ * D_;
  const short* Vg = vh + (size_t)bh * T_ * D_;
  const unsigned short* Bpu =
      (const unsigned short*)(biast + (size_t)bh * T_ * T_);

  bf16x8 qf[2];
#pragma unroll
  for (int s = 0; s < 2; ++s)
    qf[s] = *(const bf16x8*)&Qg[(size_t)(i0 + 16 * w + col) * D_ + s * 32 + quad * 8];

  float lsum[4];
  f32x4 oacc[4];
#pragma unroll
  for (int r = 0; r < 4; ++r) lsum[r] = 0.f;
#pragma unroll
  for (int dt = 0; dt < 4; ++dt) oacc[dt] = {0.f, 0.f, 0.f, 0.f};

  int jbase = half * (T_ / 2);
  for (int jj = 0; jj < T_ / 2; jj += 64) {
    int j0 = jbase + jj;
    __syncthreads();
    // stage K [j][d]
#pragma unroll
    for (int p = 0; p < 2; ++p) {
      int c = tid + p * 256;
      int row = c >> 3, dc = (c & 7) * 8;
      *(int4*)&Ks[row * 72 + dc] =
          *(const int4*)&Kg[(size_t)(j0 + row) * D_ + dc];
    }
    // stage V transposed -> Vt[d][j]
    {
      int j = tid & 63, d0 = (tid >> 6) * 16;
#pragma unroll
      for (int p = 0; p < 2; ++p) {
        short tmp[8];
        *(int4*)tmp = *(const int4*)&Vg[(size_t)(j0 + j) * D_ + d0 + p * 8];
#pragma unroll
        for (int q = 0; q < 8; ++q) Vt[(d0 + p * 8 + q) * 72 + j] = tmp[q];
      }
    }
    __syncthreads();

    // bias loads: after the barrier (not drained by it); first use is in
    // softmax, after the 8 QK MFMAs -> latency hidden.
    unsigned short bsv[4][4];
#pragma unroll
    for (int r = 0; r < 4; ++r) {
      int gi = i0 + 16 * w + quad * 4 + r;
#pragma unroll
      for (int jt = 0; jt < 4; ++jt)
        bsv[r][jt] = Bpu[(size_t)gi * T_ + j0 + 16 * jt + col];
    }

    // S = Q·K^T
    f32x4 sacc[4];
#pragma unroll
    for (int jt = 0; jt < 4; ++jt) sacc[jt] = {0.f, 0.f, 0.f, 0.f};
#pragma unroll
    for (int s = 0; s < 2; ++s) {
#pragma unroll
      for (int jt = 0; jt < 4; ++jt) {
        bf16x8 kf = *(const bf16x8*)&Ks[(16 * jt + col) * 72 + s * 32 + quad * 8];
        sacc[jt] = __builtin_amdgcn_mfma_f32_16x16x32_bf16(qf[s], kf, sacc[jt], 0, 0, 0);
      }
    }

    // fixed-shift softmax numerator; defer l reduction
#pragma unroll
    for (int r = 0; r < 4; ++r) {
      int li = 16 * w + quad * 4 + r;  // local i-row
#pragma unroll
      for (int jt = 0; jt < 4; ++jt) {
        float s = sacc[jt][r] + bf2f(bsv[r][jt]);
        float p = __expf(fminf(s - kShift, 60.0f));
        lsum[r] += p;
        Ps[li * 72 + 16 * jt + col] = f2bf(p);
      }
    }
    __syncthreads();

    // O += P·V
#pragma unroll
    for (int s = 0; s < 2; ++s) {
      bf16x8 pf = *(const bf16x8*)&Ps[(16 * w + col) * 72 + s * 32 + quad * 8];
#pragma unroll
      for (int dt = 0; dt < 4; ++dt) {
        bf16x8 vf = *(const bf16x8*)&Vt[(16 * dt + col) * 72 + s * 32 + quad * 8];
        oacc[dt] = __builtin_amdgcn_mfma_f32_16x16x32_bf16(pf, vf, oacc[dt], 0, 0, 0);
      }
    }
  }

  // epilogue: reduce l across the 16 lanes of each row, store partials
#pragma unroll
  for (int r = 0; r < 4; ++r) {
    float l = lsum[r];
#pragma unroll
    for (int o = 1; o < 16; o <<= 1) l += __shfl_xor(l, o);
    int gi = i0 + 16 * w + quad * 4 + r;
    size_t orow = (size_t)half * 32768 + (size_t)bh * T_ + gi;
    if (col == 0) lpart[orow] = l;
#pragma unroll
    for (int dt = 0; dt < 4; ++dt)
      Opart[orow * 64 + 16 * dt + col] = oacc[dt][r];
  }
}

// --------- merge halves: O=(O0+O1)/(l0+l1), store ao bf16 [B*T, C] ----------
__global__ __launch_bounds__(256) void attn_merge_kernel(
    const float* __restrict__ Opart, const float* __restrict__ lpart,
    short* __restrict__ ao) {
  int g = blockIdx.x * 256 + threadIdx.x;  // 32768 rows * 16 float4 = 524288
  int row = g >> 4, d4 = (g & 15) * 4;
  float4 o0 = *(const float4*)&Opart[(size_t)row * 64 + d4];
  float4 o1 = *(const float4*)&Opart[((size_t)32768 + row) * 64 + d4];
  float inv = 1.0f / (lpart[row] + lpart[32768 + row]);
  int bh = row >> 10, gi = row & 1023;
  int b = bh >> 3, h = bh & 7;
  short4 o;
  o.x = f2bf((o0.x + o1.x) * inv);
  o.y = f2bf((o0.y + o1.y) * inv);
  o.z = f2bf((o0.z + o1.z) * inv);
  o.w = f2bf((o0.w + o1.w) * inv);
  *(short4*)&ao[((size_t)(b * T_ + gi)) * C_ + h * D_ + d4] = o;
}

// ------------- fallback attn (round-3 path, pair fp32 + uint8 mask) ---------
__global__ __launch_bounds__(256) void attn_kernel(
    const short* __restrict__ qh, const short* __restrict__ kh,
    const short* __restrict__ vh, const float* __restrict__ pair,
    const unsigned char* __restrict__ mask, short* __restrict__ ao) {
  __shared__ short Ks[64 * 72];
  __shared__ short Vt[64 * 72];
  __shared__ short Ps[64 * 72];
  int tid = threadIdx.x;
  int lane = tid & 63, w = tid >> 6;
  int col = lane & 15, quad = lane >> 4;
  int bh = blockIdx.y;
  int b = bh >> 3, h = bh & 7;
  int i0 = blockIdx.x * 64;
  const short* Qg = qh + (size_t)bh * T_ * D_;
  const short* Kg = kh + (size_t)bh * T_ * D_;
  const short* Vg = vh + (size_t)bh * T_ * D_;

  bf16x8 qf[2];
#pragma unroll
  for (int s = 0; s < 2; ++s)
    qf[s] = *(const bf16x8*)&Qg[(size_t)(i0 + 16 * w + col) * D_ + s * 32 + quad * 8];

  float mrun[4], lrun[4];
  f32x4 oacc[4];
#pragma unroll
  for (int r = 0; r < 4; ++r) { mrun[r] = -INFINITY; lrun[r] = 0.f; }
#pragma unroll
  for (int dt = 0; dt < 4; ++dt) oacc[dt] = {0.f, 0.f, 0.f, 0.f};

  for (int j0 = 0; j0 < T_; j0 += 64) {
    __syncthreads();
#pragma unroll
    for (int p = 0; p < 2; ++p) {
      int c = tid + p * 256;
      int row = c >> 3, dc = (c & 7) * 8;
      *(int4*)&Ks[row * 72 + dc] =
          *(const int4*)&Kg[(size_t)(j0 + row) * D_ + dc];
    }
    {
      int j = tid & 63, d0 = (tid >> 6) * 16;
#pragma unroll
      for (int p = 0; p < 2; ++p) {
        short tmp[8];
        *(int4*)tmp = *(const int4*)&Vg[(size_t)(j0 + j) * D_ + d0 + p * 8];
#pragma unroll
        for (int q = 0; q < 8; ++q) Vt[(d0 + p * 8 + q) * 72 + j] = tmp[q];
      }
    }
    __syncthreads();

    f32x4 sacc[4];
#pragma unroll
    for (int jt = 0; jt < 4; ++jt) sacc[jt] = {0.f, 0.f, 0.f, 0.f};
#pragma unroll
    for (int s = 0; s < 2; ++s) {
#pragma unroll
      for (int jt = 0; jt < 4; ++jt) {
        bf16x8 kf = *(const bf16x8*)&Ks[(16 * jt + col) * 72 + s * 32 + quad * 8];
        sacc[jt] = __builtin_amdgcn_mfma_f32_16x16x32_bf16(qf[s], kf, sacc[jt], 0, 0, 0);
      }
    }

#pragma unroll
    for (int r = 0; r < 4; ++r) {
      int gi = i0 + 16 * w + quad * 4 + r;
      const float* prow = pair + (size_t)(b * T_ + gi) * (T_ * H_) + h;
      const unsigned char* mrow = mask + (size_t)(b * T_ + gi) * T_;
      float sv[4];
      float rm = -INFINITY;
#pragma unroll
      for (int jt = 0; jt < 4; ++jt) {
        int j = j0 + 16 * jt + col;
        float s = sacc[jt][r] + prow[(size_t)j * H_];
        if (!mrow[j]) s += kNeg;
        sv[jt] = s;
        rm = fmaxf(rm, s);
      }
#pragma unroll
      for (int o = 8; o > 0; o >>= 1) rm = fmaxf(rm, __shfl_xor(rm, o));
      float mnew  = fmaxf(mrun[r], rm);
      float alpha = __expf(mrun[r] - mnew);
      float psum = 0.f;
#pragma unroll
      for (int jt = 0; jt < 4; ++jt) {
        float p = __expf(sv[jt] - mnew);
        psum += p;
        Ps[(16 * w + quad * 4 + r) * 72 + 16 * jt + col] = f2bf(p);
      }
#pragma unroll
      for (int o = 8; o > 0; o >>= 1) psum += __shfl_xor(psum, o);
      lrun[r] = lrun[r] * alpha + psum;
      mrun[r] = mnew;
#pragma unroll
      for (int dt = 0; dt < 4; ++dt) oacc[dt][r] *= alpha;
    }
    __syncthreads();

#pragma unroll
    for (int s = 0; s < 2; ++s) {
      bf16x8 pf = *(const bf16x8*)&Ps[(16 * w + col) * 72 + s * 32 + quad * 8];
#pragma unroll
      for (int dt = 0; dt < 4; ++dt) {
        bf16x8 vf = *(const bf16x8*)&Vt[(16 * dt + col) * 72 + s * 32 + quad * 8];
        oacc[dt] = __builtin_amdgcn_mfma_f32_16x16x32_bf16(pf, vf, oacc[dt], 0, 0, 0);
      }
    }
  }

#pragma unroll
  for (int r = 0; r < 4; ++r) {
    int gi = i0 + 16 * w + quad * 4 + r;
    float inv = 1.0f / lrun[r];
    size_t base = (size_t)(b * T_ + gi) * C_ + h * D_;
#pragma unroll
    for (int dt = 0; dt < 4; ++dt)
      ao[base + 16 * dt + col] = f2bf(oacc[dt][r] * inv);
  }
}

// ---------------------------------------------------------------------------
extern "C" void kernel_launch(void* const* d_in, const int* in_sizes, int n_in,
                              void* d_out, int out_size, void* d_ws, size_t ws_size,
                              hipStream_t stream) {
  const float* x      = (const float*)d_in[0];
  const float* pair   = (const float*)d_in[1];
  const void*  maskraw = d_in[2];
  const float* norm_w = (const float*)d_in[3];
  const float* norm_b = (const float*)d_in[4];
  const float* qkv_w  = (const float*)d_in[5];
  const float* qkv_b  = (const float*)d_in[6];
  const float* qln_w  = (const float*)d_in[7];
  const float* qln_b  = (const float*)d_in[8];
  const float* kln_w  = (const float*)d_in[9];
  const float* kln_b  = (const float*)d_in[10];
  const float* proj_w = (const float*)d_in[11];
  const float* proj_b = (const float*)d_in[12];
  float* out = (float*)d_out;

  // d_out doubles as scratch: [0,4MB) xn bf16, [4,8MB) qh bf16.
  short* xn = (short*)d_out;
  short* qh = (short*)d_out + (size_t)BT_ * C_;

  const size_t MB = 1024 * 1024;

  if (ws_size >= 96 * MB) {
    // ws layout (r1-proven):
    //   [0,64MB)    biast bf16 [B,H,T,T] (written by prep AFTER split)
    //   [0,24MB)    qkv fp32 (live gemm->split only; overlaid by biast)
    //   [64,80MB)   Opart fp32 [2][32][1024][64]
    //   [80,80.25)  lpart fp32 [2][32][1024]
    //   [81,85MB)   ao bf16 [4096,512]
    //   [85,89MB)   kh bf16    [89,93MB) vh bf16
    //   [93,94.5MB) wq bf16    [94.5,95MB) wp bf16
    char* base = (char*)d_ws;
    short* biast = (short*)base;
    float* qkv   = (float*)base;
    float* Opart = (float*)(base + 64 * MB);
    float* lpart = (float*)(base + 80 * MB);
    short* ao    = (short*)(base + 81 * MB);
    short* kh    = (short*)(base + 85 * MB);
    short* vh    = (short*)(base + 89 * MB);
    short* wq    = (short*)(base + 93 * MB);
    short* wp    = (short*)(base + 94 * MB + 512 * 1024);

    prep_fused_kernel<<<BT_ + (N3_ * C_ + C_ * C_) / 512, 128, 0, stream>>>(
        x, norm_w, norm_b, xn, qkv_w, wq, proj_w, wp);
    gemm_bf16_kernel<<<dim3(N3_ / 64, BT_ / 128), 256, 0, stream>>>(
        xn, wq, qkv_b, qkv, BT_, N3_, C_);
    qkv_ln_split_kernel<<<BT_, 128, 0, stream>>>(
        qkv, qln_w, qln_b, kln_w, kln_b, qh, kh, vh);
    pair_prep_kernel<<<B_ * T_, 256, 0, stream>>>(pair, maskraw, biast);
    attn_split_kernel<<<dim3(T_ / 64, B_ * H_, 2), 256, 0, stream>>>(
        qh, kh, vh, biast, Opart, lpart);
    attn_merge_kernel<<<2048, 256, 0, stream>>>(Opart, lpart, ao);
    gemm_bf16_64_kernel<<<dim3(C_ / 64, BT_ / 64), 256, 0, stream>>>(
        ao, wp, proj_b, out, BT_, C_, C_);
  } else {
    // Fallback: round-3 layout (38 MB + 4B).
    float* qkv = (float*)d_ws;
    short* ao  = (short*)d_ws;
    short* sw  = (short*)d_ws;
    short* wq  = sw + (size_t)12 * 1024 * 1024;
    short* wp  = wq + (size_t)N3_ * C_;
    short* kh  = sw + (size_t)13 * 1024 * 1024;
    short* vh  = sw + (size_t)15 * 1024 * 1024;
    unsigned char* maskc = (unsigned char*)d_ws + (size_t)34 * MB;
    int* flag = (int*)((unsigned char*)d_ws + (size_t)38 * MB);

    mask_detect_kernel<<<1, 64, 0, stream>>>((const unsigned int*)maskraw, flag);
    mask_convert_kernel<<<(B_ * T_ * T_) / 1024, 256, 0, stream>>>(
        maskraw, flag, (uchar4*)maskc);
    wcvt2_kernel<<<(N3_ * C_ + C_ * C_) / 1024, 256, 0, stream>>>(
        qkv_w, wq, proj_w, wp, (N3_ * C_) / 1024);
    ln_x_kernel<<<BT_, 128, 0, stream>>>(x, norm_w, norm_b, xn);
    gemm_bf16_kernel<<<dim3(N3_ / 64, BT_ / 128), 256, 0, stream>>>(
        xn, wq, qkv_b, qkv, BT_, N3_, C_);
    qkv_ln_split_kernel<<<BT_, 128, 0, stream>>>(
        qkv, qln_w, qln_b, kln_w, kln_b, qh, kh, vh);
    attn_kernel<<<dim3(T_ / 64, B_ * H_), 256, 0, stream>>>(
        qh, kh, vh, pair, maskc, ao);
    gemm_bf16_kernel<<<dim3(C_ / 64, BT_ / 128), 256, 0, stream>>>(
        ao, wp, proj_b, out, BT_, C_, C_);
  }
}